// Round 2
// baseline (4497.718 us; speedup 1.0000x reference)
//
#include <hip/hip_runtime.h>
#include <cstdint>
#include <cstddef>

#define DIMC     512
#define D_INNER  1024
#define HEADDIM  128
#define NHEADS   8
#define D_STATE  128
#define CONV_DIM 1280
#define D_IN_PROJ 2312
#define BSZ      4
#define LSEQ     4096
#define BLTOT    (BSZ*LSEQ)   // 16384
#define NC       8            // chunks
#define CLEN     (LSEQ/NC)    // 512
#define TS       4            // t-steps per LDS staging round

// ---------------- K1: in_proj GEMM ----------------
__global__ __launch_bounds__(256) void k1_inproj(
    const float* __restrict__ x, const float* __restrict__ W,
    float* __restrict__ zbuf, float* __restrict__ xbc, float* __restrict__ dtb)
{
    __shared__ float As[32][68];
    __shared__ float Bs[32][68];
    const int tx = threadIdx.x, ty = threadIdx.y;
    const int tid = ty * 16 + tx;
    const int n0 = blockIdx.x * 64;
    const int m0 = blockIdx.y * 64;
    const int b  = m0 >> 12;
    const int l0 = m0 & 4095;

    float c[4][4] = {};
    const int am = tid & 63, ak = tid >> 6;
    const int bk = tid & 31, bn = tid >> 5;

    for (int kb = 0; kb < DIMC; kb += 32) {
        #pragma unroll
        for (int kk = 0; kk < 32; kk += 4) {
            As[ak + kk][am] = x[((size_t)(b * DIMC + kb + ak + kk) << 12) + l0 + am];
        }
        #pragma unroll
        for (int nn = 0; nn < 8; ++nn) {
            int n = bn * 8 + nn;
            int e = n0 + n;
            Bs[bk][n] = (e < D_IN_PROJ) ? W[(size_t)e * DIMC + kb + bk] : 0.f;
        }
        __syncthreads();
        #pragma unroll
        for (int kk = 0; kk < 32; ++kk) {
            float4 a4 = *(const float4*)&As[kk][ty * 4];
            float4 b4 = *(const float4*)&Bs[kk][tx * 4];
            float av_[4] = {a4.x, a4.y, a4.z, a4.w};
            float bv_[4] = {b4.x, b4.y, b4.z, b4.w};
            #pragma unroll
            for (int i = 0; i < 4; ++i)
                #pragma unroll
                for (int j = 0; j < 4; ++j)
                    c[i][j] = fmaf(av_[i], bv_[j], c[i][j]);
        }
        __syncthreads();
    }
    #pragma unroll
    for (int i = 0; i < 4; ++i) {
        int m = m0 + ty * 4 + i;
        #pragma unroll
        for (int j = 0; j < 4; ++j) {
            int e = n0 + tx * 4 + j;
            float v = c[i][j];
            if (e < D_INNER)                  zbuf[(size_t)m * D_INNER + e] = v;
            else if (e < D_INNER + CONV_DIM)  xbc[(size_t)m * CONV_DIM + (e - D_INNER)] = v;
            else if (e < D_IN_PROJ)           dtb[(size_t)m * NHEADS + (e - (D_INNER + CONV_DIM))] = v;
        }
    }
}

// ---------------- K2: softplus(dt + bias), dA ----------------
__global__ __launch_bounds__(256) void k2_dt(
    const float* __restrict__ dtb, const float* __restrict__ dt_bias,
    const float* __restrict__ A_log, float* __restrict__ dtp, float* __restrict__ dAb)
{
    int idx = blockIdx.x * 256 + threadIdx.x;
    if (idx >= BLTOT * NHEADS) return;
    int h = idx & 7;
    float v = dtb[idx] + dt_bias[h];
    float sp = (v > 20.f) ? v : log1pf(expf(v));
    dtp[idx] = sp;
    dAb[idx] = expf(sp * (-expf(A_log[h])));
}

// ---------------- K3: causal depthwise conv(4) + SiLU ----------------
__global__ __launch_bounds__(256) void k3_conv(
    const float* __restrict__ xbc, const float* __restrict__ cw,
    const float* __restrict__ cb, float* __restrict__ xbcc)
{
    int idx = blockIdx.x * 256 + threadIdx.x;
    int c = idx % CONV_DIM;
    int m = idx / CONV_DIM;
    int l = m & 4095;
    float acc = cb[c];
    #pragma unroll
    for (int j = 0; j < 4; ++j) {
        if (l - j >= 0)
            acc = fmaf(xbc[(size_t)(m - j) * CONV_DIM + c], cw[c * 4 + (3 - j)], acc);
    }
    xbcc[idx] = acc / (1.f + expf(-acc));
}

// ---------------- K4a: chunked SSM scan (local) ----------------
// block = (b, h, c, pq-group of 4). 4 waves share B/C/x rows via LDS.
// wave lane: p = pg*16 + warp*4 + (lane&3), n-range = (lane>>2)*8 .. +8
__global__ __launch_bounds__(256, 6) void k4a_scan(
    const float* __restrict__ xbcc, const float* __restrict__ dtp,
    const float* __restrict__ dAb, const float* __restrict__ Dp,
    float* __restrict__ ybuf, float* __restrict__ statebuf, float* __restrict__ dcum)
{
    __shared__ float4 sBC[2][TS][64];   // per t: B (q 0..31), C (q 32..63)
    __shared__ float4 sX[2][TS][4];     // 16 x-values (this block's p range)
    __shared__ float  sAD[2][TS][2];    // dA, dt

    const int tid  = threadIdx.x;
    const int lane = tid & 63;
    const int warp = tid >> 6;
    const int pg = blockIdx.x & 7;
    const int c  = (blockIdx.x >> 3) & 7;
    const int h  = (blockIdx.x >> 6) & 7;
    const int b  = blockIdx.x >> 9;
    const int p  = pg * 16 + warp * 4 + (lane & 3);
    const int nq = (lane >> 2) * 2;     // float4 index of this lane's n-range
    const float Dh = Dp[h];
    const size_t mbase = (size_t)b * LSEQ + c * CLEN;

    const int ld_t = tid >> 6;
    const int ld_q = tid & 63;

    auto stage = [&](int buf, int r) {
        int t0 = r * TS;
        {
            const float* row = xbcc + (mbase + t0 + ld_t) * CONV_DIM;
            sBC[buf][ld_t][ld_q] = *(const float4*)(row + D_INNER + ld_q * 4);
        }
        if (tid < 16) {
            int tl = tid >> 2, j = tid & 3;
            const float* row = xbcc + (mbase + t0 + tl) * CONV_DIM;
            sX[buf][tl][j] = *(const float4*)(row + h * HEADDIM + pg * 16 + j * 4);
        } else if (tid < 24) {
            int tl = (tid - 16) >> 1, k = tid & 1;
            size_t idx = (mbase + t0 + tl) * NHEADS + h;
            sAD[buf][tl][k] = k ? dtp[idx] : dAb[idx];
        }
    };

    stage(0, 0);
    __syncthreads();

    float s0=0.f,s1=0.f,s2=0.f,s3=0.f,s4=0.f,s5=0.f,s6=0.f,s7=0.f;
    float cum = 1.f;
    const bool store_dc = (pg == 0 && tid == 0);
    float* dcp = dcum + (size_t)(b * NHEADS + h) * LSEQ + c * CLEN;

    const int NR = CLEN / TS;
    for (int r = 0; r < NR; ++r) {
        const int buf = r & 1;
        if (r + 1 < NR) stage(buf ^ 1, r + 1);
        #pragma unroll
        for (int tl = 0; tl < TS; ++tl) {
            const float4 b0 = sBC[buf][tl][nq];
            const float4 b1 = sBC[buf][tl][nq + 1];
            const float4 c0 = sBC[buf][tl][32 + nq];
            const float4 c1 = sBC[buf][tl][32 + nq + 1];
            const float xt  = ((const float*)&sX[buf][tl][0])[warp * 4 + (lane & 3)];
            const float dAt = sAD[buf][tl][0];
            const float dtt = sAD[buf][tl][1];

            const float dtx = dtt * xt;
            float y0, y1;
            s0 = fmaf(s0, dAt, dtx * b0.x); y0 = s0 * c0.x;
            s1 = fmaf(s1, dAt, dtx * b0.y); y1 = s1 * c0.y;
            s2 = fmaf(s2, dAt, dtx * b0.z); y0 = fmaf(s2, c0.z, y0);
            s3 = fmaf(s3, dAt, dtx * b0.w); y1 = fmaf(s3, c0.w, y1);
            s4 = fmaf(s4, dAt, dtx * b1.x); y0 = fmaf(s4, c1.x, y0);
            s5 = fmaf(s5, dAt, dtx * b1.y); y1 = fmaf(s5, c1.y, y1);
            s6 = fmaf(s6, dAt, dtx * b1.z); y0 = fmaf(s6, c1.z, y0);
            s7 = fmaf(s7, dAt, dtx * b1.w); y1 = fmaf(s7, c1.w, y1);
            float y = y0 + y1;
            y += __shfl_xor(y, 4);
            y += __shfl_xor(y, 8);
            y += __shfl_xor(y, 16);
            y += __shfl_xor(y, 32);
            cum *= dAt;
            if (store_dc) dcp[r * TS + tl] = cum;
            if ((lane >> 2) == 0) {
                ybuf[(mbase + r * TS + tl) * D_INNER + h * HEADDIM + p] = fmaf(Dh, xt, y);
            }
        }
        __syncthreads();
    }

    float* sb = statebuf + ((((size_t)(b * NHEADS + h) * NC + c) * HEADDIM + p) * D_STATE + nq * 4);
    *(float4*)sb       = make_float4(s0, s1, s2, s3);
    *(float4*)(sb + 4) = make_float4(s4, s5, s6, s7);
}

// ---------------- K4b: cross-chunk state prefix (in place) ----------------
// statebuf[bh][c][p][n]: final local chunk states -> becomes s_init[c]
__global__ __launch_bounds__(256) void k4b_prefix(
    float* __restrict__ statebuf, const float* __restrict__ dcum)
{
    const int bh = blockIdx.x;       // 0..31
    const int tid = threadIdx.x;
    float P[NC];
    #pragma unroll
    for (int c = 0; c < NC; ++c)
        P[c] = dcum[(size_t)bh * LSEQ + c * CLEN + (CLEN - 1)];
    float* base = statebuf + (size_t)bh * NC * HEADDIM * D_STATE;
    for (int k = tid; k < HEADDIM * D_STATE / 4; k += 256) {
        float4 s = {0.f, 0.f, 0.f, 0.f};
        #pragma unroll
        for (int c = 0; c < NC; ++c) {
            float4* ptr = (float4*)(base + (size_t)c * HEADDIM * D_STATE) + k;
            float4 f = *ptr;
            *ptr = s;                 // s_init[c] overwrites final[c]
            s.x = fmaf(s.x, P[c], f.x);
            s.y = fmaf(s.y, P[c], f.y);
            s.z = fmaf(s.z, P[c], f.z);
            s.w = fmaf(s.w, P[c], f.w);
        }
    }
}

// ---------------- K4c: fix-up y += cumdA_t * (C_t . s_init) ----------------
// block = (b, h, c, p-tile of 32). thread: p = pt*32 + (tid>>3), n-range (tid&7)*16
__global__ __launch_bounds__(256, 4) void k4c_fix(
    const float* __restrict__ xbcc, const float* __restrict__ sinit,
    const float* __restrict__ dcum, float* __restrict__ ybuf)
{
    const int pt = blockIdx.x & 3;
    const int c  = (blockIdx.x >> 2) & 7;
    const int h  = (blockIdx.x >> 5) & 7;
    const int b  = blockIdx.x >> 8;
    if (c == 0) return;               // s_init[0] == 0
    const int tid = threadIdx.x;
    const int ng = tid & 7;
    const int p  = pt * 32 + (tid >> 3);

    const float* sp = sinit + ((((size_t)(b * NHEADS + h) * NC + c) * HEADDIM + p) * D_STATE + ng * 16);
    const float4 s0 = *(const float4*)sp;
    const float4 s1 = *(const float4*)(sp + 4);
    const float4 s2 = *(const float4*)(sp + 8);
    const float4 s3 = *(const float4*)(sp + 12);

    const size_t mbase = (size_t)b * LSEQ + c * CLEN;
    const float* dcp = dcum + (size_t)(b * NHEADS + h) * LSEQ + c * CLEN;

    float4 Ca[4], Cb[4];
    auto loadC = [&](int t, float4* Cv) {
        const float* row = xbcc + (mbase + t) * CONV_DIM + D_INNER + D_STATE + ng * 16;
        Cv[0] = *(const float4*)(row);
        Cv[1] = *(const float4*)(row + 4);
        Cv[2] = *(const float4*)(row + 8);
        Cv[3] = *(const float4*)(row + 12);
    };
    loadC(0, Ca);

    for (int t = 0; t < CLEN; ++t) {
        float4* Cc = (t & 1) ? Cb : Ca;
        float4* Cn = (t & 1) ? Ca : Cb;
        if (t + 1 < CLEN) loadC(t + 1, Cn);
        float acc;
        acc = s0.x * Cc[0].x;
        acc = fmaf(s0.y, Cc[0].y, acc);
        acc = fmaf(s0.z, Cc[0].z, acc);
        acc = fmaf(s0.w, Cc[0].w, acc);
        acc = fmaf(s1.x, Cc[1].x, acc);
        acc = fmaf(s1.y, Cc[1].y, acc);
        acc = fmaf(s1.z, Cc[1].z, acc);
        acc = fmaf(s1.w, Cc[1].w, acc);
        acc = fmaf(s2.x, Cc[2].x, acc);
        acc = fmaf(s2.y, Cc[2].y, acc);
        acc = fmaf(s2.z, Cc[2].z, acc);
        acc = fmaf(s2.w, Cc[2].w, acc);
        acc = fmaf(s3.x, Cc[3].x, acc);
        acc = fmaf(s3.y, Cc[3].y, acc);
        acc = fmaf(s3.z, Cc[3].z, acc);
        acc = fmaf(s3.w, Cc[3].w, acc);
        acc += __shfl_xor(acc, 1);
        acc += __shfl_xor(acc, 2);
        acc += __shfl_xor(acc, 4);
        const float dc = dcp[t];
        if (ng == 0) {
            const size_t yi = (mbase + t) * D_INNER + h * HEADDIM + p;
            ybuf[yi] += dc * acc;
        }
    }
}

// ---------------- K5: y *= silu(z); RMSNorm * norm_w ----------------
__global__ __launch_bounds__(256) void k5_norm(
    float* __restrict__ ybuf, const float* __restrict__ zbuf, const float* __restrict__ nw)
{
    const int m = blockIdx.x;
    const int tid = threadIdx.x;
    const size_t off = (size_t)m * D_INNER + tid * 4;
    float4 yv = *(const float4*)(ybuf + off);
    float4 zv = *(const float4*)(zbuf + off);
    float4 g;
    g.x = yv.x * (zv.x / (1.f + expf(-zv.x)));
    g.y = yv.y * (zv.y / (1.f + expf(-zv.y)));
    g.z = yv.z * (zv.z / (1.f + expf(-zv.z)));
    g.w = yv.w * (zv.w / (1.f + expf(-zv.w)));
    float ss = g.x*g.x + g.y*g.y + g.z*g.z + g.w*g.w;
    #pragma unroll
    for (int mask = 1; mask <= 32; mask <<= 1) ss += __shfl_xor(ss, mask);
    __shared__ float red[4];
    if ((tid & 63) == 0) red[tid >> 6] = ss;
    __syncthreads();
    float tot = red[0] + red[1] + red[2] + red[3];
    float scale = rsqrtf(tot * (1.f / 1024.f) + 1e-5f);
    float4 w4 = *(const float4*)(nw + tid * 4);
    g.x *= scale * w4.x;
    g.y *= scale * w4.y;
    g.z *= scale * w4.z;
    g.w *= scale * w4.w;
    *(float4*)(ybuf + off) = g;
}

// ---------------- K6: out_proj GEMM + residual (transposed store) ----------------
__global__ __launch_bounds__(256) void k6_outproj(
    const float* __restrict__ y, const float* __restrict__ W,
    const float* __restrict__ x, float* __restrict__ out)
{
    __shared__ float As[32][68];
    __shared__ float Bs[32][68];
    const int tx = threadIdx.x, ty = threadIdx.y;
    const int tid = ty * 16 + tx;
    const int n0 = blockIdx.x * 64;
    const int m0 = blockIdx.y * 64;
    const int b  = m0 >> 12;
    const int l0 = m0 & 4095;

    float c[4][4] = {};
    const int lk = tid & 31, lr = tid >> 5;

    for (int kb = 0; kb < D_INNER; kb += 32) {
        #pragma unroll
        for (int mm = 0; mm < 8; ++mm) {
            int m = lr * 8 + mm;
            As[lk][m] = y[(size_t)(m0 + m) * D_INNER + kb + lk];
        }
        #pragma unroll
        for (int nn = 0; nn < 8; ++nn) {
            int n = lr * 8 + nn;
            Bs[lk][n] = W[(size_t)(n0 + n) * D_INNER + kb + lk];
        }
        __syncthreads();
        #pragma unroll
        for (int kk = 0; kk < 32; ++kk) {
            float4 a4 = *(const float4*)&As[kk][tx * 4];
            float4 b4 = *(const float4*)&Bs[kk][ty * 4];
            float av_[4] = {a4.x, a4.y, a4.z, a4.w};
            float bv_[4] = {b4.x, b4.y, b4.z, b4.w};
            #pragma unroll
            for (int i = 0; i < 4; ++i)
                #pragma unroll
                for (int j = 0; j < 4; ++j)
                    c[i][j] = fmaf(bv_[i], av_[j], c[i][j]);
        }
        __syncthreads();
    }
    #pragma unroll
    for (int i = 0; i < 4; ++i) {
        int d = n0 + ty * 4 + i;
        size_t o = ((size_t)(b * DIMC + d) << 12) + l0 + tx * 4;
        float4 xr = *(const float4*)(x + o);
        float4 r;
        r.x = c[i][0] + xr.x;
        r.y = c[i][1] + xr.y;
        r.z = c[i][2] + xr.z;
        r.w = c[i][3] + xr.w;
        *(float4*)(out + o) = r;
    }
}

extern "C" void kernel_launch(void* const* d_in, const int* in_sizes, int n_in,
                              void* d_out, int out_size, void* d_ws, size_t ws_size,
                              hipStream_t stream) {
    const float* x          = (const float*)d_in[0];
    const float* in_proj_w  = (const float*)d_in[1];
    const float* conv_w     = (const float*)d_in[2];
    const float* conv_b     = (const float*)d_in[3];
    const float* dt_bias    = (const float*)d_in[4];
    const float* A_log      = (const float*)d_in[5];
    const float* D_param    = (const float*)d_in[6];
    const float* norm_w     = (const float*)d_in[7];
    const float* out_proj_w = (const float*)d_in[8];
    float* out = (float*)d_out;

    float* ws   = (float*)d_ws;
    float* zbuf = ws;                                   // BLTOT*1024
    float* xbc  = zbuf + (size_t)BLTOT * D_INNER;       // BLTOT*1280 (pre-conv)
    float* xbcc = xbc  + (size_t)BLTOT * CONV_DIM;      // BLTOT*1280 (post conv+silu)
    float* dtb  = xbcc + (size_t)BLTOT * CONV_DIM;      // BLTOT*8
    float* dtp  = dtb  + (size_t)BLTOT * NHEADS;        // BLTOT*8
    float* dAb  = dtp  + (size_t)BLTOT * NHEADS;        // BLTOT*8
    float* ybuf = xbc;           // pre-conv xbc dead after K3
    float* dcum = dtb;           // dtb dead after K2 (131072 floats, exact fit)
    float* statebuf = out;       // 16.8 MB scratch inside d_out (33.5 MB); K6 overwrites all

    k1_inproj<<<dim3(37, 256), dim3(16, 16), 0, stream>>>(x, in_proj_w, zbuf, xbc, dtb);
    k2_dt<<<dim3(512), dim3(256), 0, stream>>>(dtb, dt_bias, A_log, dtp, dAb);
    k3_conv<<<dim3(81920), dim3(256), 0, stream>>>(xbc, conv_w, conv_b, xbcc);
    k4a_scan<<<dim3(2048), dim3(256), 0, stream>>>(xbcc, dtp, dAb, D_param, ybuf, statebuf, dcum);
    k4b_prefix<<<dim3(32), dim3(256), 0, stream>>>(statebuf, dcum);
    k4c_fix<<<dim3(1024), dim3(256), 0, stream>>>(xbcc, statebuf, dcum, ybuf);
    k5_norm<<<dim3(BLTOT), dim3(256), 0, stream>>>(ybuf, zbuf, norm_w);
    k6_outproj<<<dim3(8, 256), dim3(16, 16), 0, stream>>>(ybuf, out_proj_w, x, out);
}